// Round 7
// baseline (295.887 us; speedup 1.0000x reference)
//
#include <hip/hip_runtime.h>
#include <hip/hip_cooperative_groups.h>

namespace cg = cooperative_groups;

// ---------------------------------------------------------------------------
// GCN 2-layer forward.
//   k_csr (cooperative, 1 launch): zero cnt -> hist -> scan(+dinv) -> scatter
//          builds CSR of (src,norm) int2 pairs grouped by dst.
//   k_gemm1: H1b = bf16(x@W1)                      [n,128] ushort
//   k_agg1g2: per 32-row block:
//        AGG_lds = relu(b1 + H1b*dinv^2 + gather(H1b))   (LDS only, never global)
//        H3b = bf16(AGG_lds @ W2)                  [n,40] ushort
//   k_agg2: OUT = b2 + H3b*dinv^2 + gather(H3b)    fp32
// ---------------------------------------------------------------------------

__device__ inline unsigned short f2bf(float x) {
    unsigned u = __float_as_uint(x);
    unsigned r = (u + 0x7FFFu + ((u >> 16) & 1u)) >> 16;   // round-nearest-even
    return (unsigned short)r;
}
__device__ inline float bflo(unsigned u) { return __uint_as_float(u << 16); }
__device__ inline float bfhi(unsigned u) { return __uint_as_float(u & 0xFFFF0000u); }

// unpack uint4 (8 bf16) and fma into acc[8]
__device__ inline void fma8(float* acc, uint4 uv, float wt) {
    acc[0] = fmaf(bflo(uv.x), wt, acc[0]);
    acc[1] = fmaf(bfhi(uv.x), wt, acc[1]);
    acc[2] = fmaf(bflo(uv.y), wt, acc[2]);
    acc[3] = fmaf(bfhi(uv.y), wt, acc[3]);
    acc[4] = fmaf(bflo(uv.z), wt, acc[4]);
    acc[5] = fmaf(bfhi(uv.z), wt, acc[5]);
    acc[6] = fmaf(bflo(uv.w), wt, acc[6]);
    acc[7] = fmaf(bfhi(uv.w), wt, acc[7]);
}

// ---- cooperative CSR build: grid MUST be 256 blocks x 256 threads ----------
// n=50000 -> nb=196 scan blocks <= gridDim; bsum scan fits one 256-thread block.
__global__ __launch_bounds__(256) void k_csr(
    const int* __restrict__ src, const int* __restrict__ dst,
    int* __restrict__ cnt, int* __restrict__ rowstart,
    int* __restrict__ bsum, int* __restrict__ boff,
    int* __restrict__ cursor, float* __restrict__ dinv,
    int2* __restrict__ epair, int n, int m)
{
    cg::grid_group grid = cg::this_grid();
    const int t   = threadIdx.x;
    const int b   = blockIdx.x;
    const int gid = b * 256 + t;
    const int gsz = gridDim.x * 256;
    const int nb  = (n + 255) / 256;
    __shared__ int s[256];

    // P0: zero counts
    for (int i = gid; i < n; i += gsz) cnt[i] = 0;
    grid.sync();

    // P1: degree histogram
    for (int e = gid; e < m; e += gsz) atomicAdd(&cnt[dst[e]], 1);
    grid.sync();

    // P2: block-local scan + dinv
    if (b < nb) {
        int i = b * 256 + t;
        int v = (i < n) ? cnt[i] : 0;
        if (i < n) dinv[i] = rsqrtf((float)v + 1.0f);
        s[t] = v;
        __syncthreads();
#pragma unroll
        for (int off = 1; off < 256; off <<= 1) {
            int x = s[t];
            if (t >= off) x += s[t - off];
            __syncthreads();
            s[t] = x;
            __syncthreads();
        }
        if (i < n) rowstart[i] = s[t] - v;        // block-local exclusive
        if (t == 255) bsum[b] = s[255];
    }
    grid.sync();

    // P3: scan block sums (block 0 only; nb <= 256)
    if (b == 0) {
        int v = (t < nb) ? bsum[t] : 0;
        s[t] = v;
        __syncthreads();
#pragma unroll
        for (int off = 1; off < 256; off <<= 1) {
            int x = s[t];
            if (t >= off) x += s[t - off];
            __syncthreads();
            s[t] = x;
            __syncthreads();
        }
        if (t < nb) boff[t] = s[t] - v;
    }
    grid.sync();

    // P4: globalize offsets + init cursors
    for (int i = gid; i < n; i += gsz) {
        int v = rowstart[i] + boff[i >> 8];
        rowstart[i] = v;
        cursor[i]   = v;
    }
    if (gid == 0) rowstart[n] = m;
    grid.sync();

    // P5: scatter (src, norm) pairs into CSR order
    for (int e = gid; e < m; e += gsz) {
        int sr = src[e], d = dst[e];
        int pos = atomicAdd(&cursor[d], 1);
        epair[pos] = make_int2(sr, __float_as_int(dinv[sr] * dinv[d]));
    }
}

// GEMM1: [n,128] @ [128,128] fp32; 128x128 tile, 8x8 micro-tile; bf16 output.
__global__ __launch_bounds__(256) void k_gemm1(
    const float* __restrict__ X, const float* __restrict__ W,
    unsigned short* __restrict__ Hb, int n)
{
    __shared__ float xs[128][36];
    __shared__ float ws[32][128];
    const int t  = threadIdx.x;
    const int tx = t & 15;
    const int ty = t >> 4;
    const int r0 = blockIdx.x * 128;
    float acc[8][8] = {};

    for (int kc = 0; kc < 128; kc += 32) {
#pragma unroll
        for (int i = 0; i < 4; ++i) {
            int idx = t + i * 256;
            int row = idx >> 3;
            int q   = idx & 7;
            int r   = r0 + row;
            float4 v = make_float4(0.f, 0.f, 0.f, 0.f);
            if (r < n) v = *(const float4*)&X[(size_t)r * 128 + kc + q * 4];
            *(float4*)&xs[row][q * 4] = v;
        }
#pragma unroll
        for (int i = 0; i < 4; ++i) {
            int idx = t + i * 256;
            int kk  = idx >> 5;
            int cg2 = idx & 31;
            *(float4*)&ws[kk][cg2 * 4] = *(const float4*)&W[(size_t)(kc + kk) * 128 + cg2 * 4];
        }
        __syncthreads();
#pragma unroll
        for (int kk = 0; kk < 32; ++kk) {
            float xv[8];
#pragma unroll
            for (int i = 0; i < 8; ++i) xv[i] = xs[ty + 16 * i][kk];
            float4 w0 = *(const float4*)&ws[kk][tx * 8];
            float4 w1 = *(const float4*)&ws[kk][tx * 8 + 4];
#pragma unroll
            for (int i = 0; i < 8; ++i) {
                acc[i][0] = fmaf(xv[i], w0.x, acc[i][0]);
                acc[i][1] = fmaf(xv[i], w0.y, acc[i][1]);
                acc[i][2] = fmaf(xv[i], w0.z, acc[i][2]);
                acc[i][3] = fmaf(xv[i], w0.w, acc[i][3]);
                acc[i][4] = fmaf(xv[i], w1.x, acc[i][4]);
                acc[i][5] = fmaf(xv[i], w1.y, acc[i][5]);
                acc[i][6] = fmaf(xv[i], w1.z, acc[i][6]);
                acc[i][7] = fmaf(xv[i], w1.w, acc[i][7]);
            }
        }
        __syncthreads();
    }

#pragma unroll
    for (int i = 0; i < 8; ++i) {
        int r = r0 + ty + 16 * i;
        if (r < n) {
            ushort4 o0 = make_ushort4(f2bf(acc[i][0]), f2bf(acc[i][1]),
                                      f2bf(acc[i][2]), f2bf(acc[i][3]));
            ushort4 o1 = make_ushort4(f2bf(acc[i][4]), f2bf(acc[i][5]),
                                      f2bf(acc[i][6]), f2bf(acc[i][7]));
            *(ushort4*)&Hb[(size_t)r * 128 + tx * 8]     = o0;
            *(ushort4*)&Hb[(size_t)r * 128 + tx * 8 + 4] = o1;
        }
    }
}

// Fused layer-1 aggregation + GEMM2. 32 rows per 256-thread block.
//   gather phase: 16 lanes/row x 8ch, 4-way unrolled, relu -> LDS tile
//   matmul phase: tile[32][128] @ W2(LDS)[128][40] -> H3b (bf16)
__global__ __launch_bounds__(256) void k_agg1g2(
    const int* __restrict__ rowstart, const int2* __restrict__ epair,
    const unsigned short* __restrict__ Hb, const float* __restrict__ B1,
    const float* __restrict__ W2, const float* __restrict__ dinv,
    unsigned short* __restrict__ H3b, int n)
{
    __shared__ float tile[32][132];     // +4 pad: conflict-free column reads
    __shared__ float ws2[128 * 40];
    const int t  = threadIdx.x;
    const int r0 = blockIdx.x * 32;

#pragma unroll
    for (int i = 0; i < 20; ++i) ws2[t + i * 256] = W2[t + i * 256];

    const int lane = t & 15;
    for (int rr = t >> 4; rr < 32; rr += 16) {
        int r = r0 + rr;
        if (r < n) {
            float di = dinv[r], d2 = di * di;
            uint4 hu = *(const uint4*)&Hb[(size_t)r * 128 + lane * 8];
            float a0[8], a1[8] = {}, a2[8] = {}, a3[8] = {};
            {
                const float* bp = &B1[lane * 8];
                float h[8] = {bflo(hu.x), bfhi(hu.x), bflo(hu.y), bfhi(hu.y),
                              bflo(hu.z), bfhi(hu.z), bflo(hu.w), bfhi(hu.w)};
#pragma unroll
                for (int c = 0; c < 8; ++c) a0[c] = fmaf(h[c], d2, bp[c]);
            }
            int j  = rowstart[r];
            int j1 = rowstart[r + 1];
            for (; j + 4 <= j1; j += 4) {
                int2 p0 = epair[j], p1 = epair[j + 1], p2 = epair[j + 2], p3 = epair[j + 3];
                uint4 u0 = *(const uint4*)&Hb[(size_t)p0.x * 128 + lane * 8];
                uint4 u1 = *(const uint4*)&Hb[(size_t)p1.x * 128 + lane * 8];
                uint4 u2 = *(const uint4*)&Hb[(size_t)p2.x * 128 + lane * 8];
                uint4 u3 = *(const uint4*)&Hb[(size_t)p3.x * 128 + lane * 8];
                fma8(a0, u0, __int_as_float(p0.y));
                fma8(a1, u1, __int_as_float(p1.y));
                fma8(a2, u2, __int_as_float(p2.y));
                fma8(a3, u3, __int_as_float(p3.y));
            }
            for (; j < j1; ++j) {
                int2 pe = epair[j];
                uint4 u = *(const uint4*)&Hb[(size_t)pe.x * 128 + lane * 8];
                fma8(a0, u, __int_as_float(pe.y));
            }
            float* p = &tile[rr][lane * 8];
#pragma unroll
            for (int c = 0; c < 8; ++c)
                p[c] = fmaxf(a0[c] + a1[c] + a2[c] + a3[c], 0.f);   // fused ReLU
        }
    }
    __syncthreads();

    // matmul: each thread = 1 row x 5 cols
    int r = r0 + (t >> 3);
    if (r < n) {
        const int c0 = (t & 7) * 5;
        const float* arow = tile[t >> 3];
        float acc[5] = {};
#pragma unroll 4
        for (int kk = 0; kk < 128; ++kk) {
            float a = arow[kk];
            const float* wp = &ws2[kk * 40 + c0];
#pragma unroll
            for (int j = 0; j < 5; ++j) acc[j] = fmaf(a, wp[j], acc[j]);
        }
#pragma unroll
        for (int j = 0; j < 5; ++j)
            H3b[(size_t)r * 40 + c0 + j] = f2bf(acc[j]);
    }
}

// layer-2 aggregation: 5 lanes/row, 8 ch each (uint4 = 16B), 320-thread blocks
__global__ __launch_bounds__(320) void k_agg2(
    const int* __restrict__ rowstart, const int2* __restrict__ epair,
    const unsigned short* __restrict__ H3b, const float* __restrict__ B,
    const float* __restrict__ dinv, float* __restrict__ OUT, int n)
{
    int t = threadIdx.x;
    int r = blockIdx.x * 64 + t / 5;
    int q = t % 5;
    if (r >= n) return;
    float di = dinv[r], d2 = di * di;
    uint4 hu = *(const uint4*)&H3b[(size_t)r * 40 + q * 8];
    float a0[8], a1[8] = {}, a2[8] = {}, a3[8] = {};
    {
        const float* bp = &B[q * 8];
        float h[8] = {bflo(hu.x), bfhi(hu.x), bflo(hu.y), bfhi(hu.y),
                      bflo(hu.z), bfhi(hu.z), bflo(hu.w), bfhi(hu.w)};
#pragma unroll
        for (int c = 0; c < 8; ++c) a0[c] = fmaf(h[c], d2, bp[c]);
    }
    int j  = rowstart[r];
    int j1 = rowstart[r + 1];
    for (; j + 4 <= j1; j += 4) {
        int2 p0 = epair[j], p1 = epair[j + 1], p2 = epair[j + 2], p3 = epair[j + 3];
        uint4 u0 = *(const uint4*)&H3b[(size_t)p0.x * 40 + q * 8];
        uint4 u1 = *(const uint4*)&H3b[(size_t)p1.x * 40 + q * 8];
        uint4 u2 = *(const uint4*)&H3b[(size_t)p2.x * 40 + q * 8];
        uint4 u3 = *(const uint4*)&H3b[(size_t)p3.x * 40 + q * 8];
        fma8(a0, u0, __int_as_float(p0.y));
        fma8(a1, u1, __int_as_float(p1.y));
        fma8(a2, u2, __int_as_float(p2.y));
        fma8(a3, u3, __int_as_float(p3.y));
    }
    for (; j < j1; ++j) {
        int2 pe = epair[j];
        uint4 u = *(const uint4*)&H3b[(size_t)pe.x * 40 + q * 8];
        fma8(a0, u, __int_as_float(pe.y));
    }
    float o[8];
#pragma unroll
    for (int c = 0; c < 8; ++c) o[c] = a0[c] + a1[c] + a2[c] + a3[c];
    float* p = &OUT[(size_t)r * 40 + q * 8];
    *(float4*)(p)     = make_float4(o[0], o[1], o[2], o[3]);
    *(float4*)(p + 4) = make_float4(o[4], o[5], o[6], o[7]);
}

extern "C" void kernel_launch(void* const* d_in, const int* in_sizes, int n_in,
                              void* d_out, int out_size, void* d_ws, size_t ws_size,
                              hipStream_t stream) {
    const float* x  = (const float*)d_in[0];
    const int*   ei = (const int*)d_in[1];
    const float* W1 = (const float*)d_in[2];
    const float* b1 = (const float*)d_in[3];
    const float* W2 = (const float*)d_in[4];
    const float* b2 = (const float*)d_in[5];
    float* out = (float*)d_out;

    const int n = in_sizes[0] / 128;     // 50000
    const int m = in_sizes[1] / 2;       // 600000
    const int* src = ei;
    const int* dst = ei + m;

    char* p = (char*)d_ws;
    auto take = [&](size_t bytes) { char* q = p; p += (bytes + 255) & ~(size_t)255; return q; };
    int*   cnt      = (int*)take(sizeof(int) * n);
    int*   rowstart = (int*)take(sizeof(int) * (n + 1));
    int*   cursor   = (int*)take(sizeof(int) * n);
    int*   bsum     = (int*)take(sizeof(int) * 256);
    int*   boff     = (int*)take(sizeof(int) * 256);
    int2*  epair    = (int2*)take(sizeof(int2) * m);
    float* dinv     = (float*)take(sizeof(float) * n);
    unsigned short* H1b = (unsigned short*)take(sizeof(short) * (size_t)n * 128);
    unsigned short* H3b = (unsigned short*)take(sizeof(short) * (size_t)n * 40);

    {
        // cooperative CSR build: 256 blocks (1/CU, trivially co-resident)
        int nn = n, mm = m;
        void* args[] = {(void*)&src, (void*)&dst, (void*)&cnt, (void*)&rowstart,
                        (void*)&bsum, (void*)&boff, (void*)&cursor, (void*)&dinv,
                        (void*)&epair, (void*)&nn, (void*)&mm};
        hipLaunchCooperativeKernel((void*)k_csr, dim3(256), dim3(256), args, 0, stream);
    }

    k_gemm1 <<<(n + 127) / 128, 256, 0, stream>>>(x, W1, H1b, n);
    k_agg1g2<<<(n + 31) / 32, 256, 0, stream>>>(rowstart, epair, H1b, b1, W2, dinv, H3b, n);
    k_agg2  <<<(n + 63) / 64, 320, 0, stream>>>(rowstart, epair, H3b, b2, dinv, out, n);
}

// Round 8
// 213.101 us; speedup vs baseline: 1.3885x; 1.3885x over previous
//
#include <hip/hip_runtime.h>
#include <hip/hip_cooperative_groups.h>

namespace cg = cooperative_groups;

// ---------------------------------------------------------------------------
// GCN 2-layer forward. 6 launches:
//   k_zero:      cnt = 0
//   k_gemm1:     hist prologue (atomicAdd cnt[dst]) + H1b = bf16(x@W1)
//   k_scan_coop: (cooperative, 196 blocks) scan cnt -> rowstart/cursor, dinv
//   k_scatter:   CSR scatter of (src, norm) int2 pairs grouped by dst
//   k_agg1g2:    AGG_lds = relu(b1 + H1b*dinv^2 + gather(H1b)); H3b = bf16(AGG@W2)
//   k_agg2:      OUT = b2 + H3b*dinv^2 + gather(H3b)
// ---------------------------------------------------------------------------

__device__ inline unsigned short f2bf(float x) {
    unsigned u = __float_as_uint(x);
    unsigned r = (u + 0x7FFFu + ((u >> 16) & 1u)) >> 16;   // round-nearest-even
    return (unsigned short)r;
}
__device__ inline float bflo(unsigned u) { return __uint_as_float(u << 16); }
__device__ inline float bfhi(unsigned u) { return __uint_as_float(u & 0xFFFF0000u); }

// unpack uint4 (8 bf16) and fma into acc[8]
__device__ inline void fma8(float* acc, uint4 uv, float wt) {
    acc[0] = fmaf(bflo(uv.x), wt, acc[0]);
    acc[1] = fmaf(bfhi(uv.x), wt, acc[1]);
    acc[2] = fmaf(bflo(uv.y), wt, acc[2]);
    acc[3] = fmaf(bfhi(uv.y), wt, acc[3]);
    acc[4] = fmaf(bflo(uv.z), wt, acc[4]);
    acc[5] = fmaf(bfhi(uv.z), wt, acc[5]);
    acc[6] = fmaf(bflo(uv.w), wt, acc[6]);
    acc[7] = fmaf(bfhi(uv.w), wt, acc[7]);
}

__global__ __launch_bounds__(256) void k_zero(int* __restrict__ cnt, int n) {
    int i = blockIdx.x * 256 + threadIdx.x;
    if (i < n) cnt[i] = 0;
}

// cooperative scan: gridDim.x MUST be nb = ceil(n/256) <= 256
__global__ __launch_bounds__(256) void k_scan_coop(
    const int* __restrict__ cnt, int* __restrict__ rowstart,
    int* __restrict__ cursor, float* __restrict__ dinv,
    int* __restrict__ bsum, int* __restrict__ boff, int n, int m)
{
    cg::grid_group grid = cg::this_grid();
    __shared__ int s[256];
    const int t = threadIdx.x;
    const int b = blockIdx.x;
    const int i = b * 256 + t;
    const int nb = gridDim.x;

    // P1: block-local scan + dinv
    int v = (i < n) ? cnt[i] : 0;
    if (i < n) dinv[i] = rsqrtf((float)v + 1.0f);
    s[t] = v;
    __syncthreads();
#pragma unroll
    for (int off = 1; off < 256; off <<= 1) {
        int x = s[t];
        if (t >= off) x += s[t - off];
        __syncthreads();
        s[t] = x;
        __syncthreads();
    }
    const int exv = s[t] - v;                 // block-local exclusive
    if (t == 255) bsum[b] = s[255];
    grid.sync();

    // P2: block 0 scans the block sums (nb <= 256)
    if (b == 0) {
        int vv = (t < nb) ? bsum[t] : 0;
        s[t] = vv;
        __syncthreads();
#pragma unroll
        for (int off = 1; off < 256; off <<= 1) {
            int x = s[t];
            if (t >= off) x += s[t - off];
            __syncthreads();
            s[t] = x;
            __syncthreads();
        }
        if (t < nb) boff[t] = s[t] - vv;
    }
    grid.sync();

    // P3: globalize + init cursor
    if (i < n) {
        int r = exv + boff[b];
        rowstart[i] = r;
        cursor[i]   = r;
    }
    if (i == 0) rowstart[n] = m;
}

__global__ __launch_bounds__(256) void k_scatter(const int* __restrict__ src,
                                                 const int* __restrict__ dst,
                                                 const float* __restrict__ dinv,
                                                 int* __restrict__ cursor,
                                                 int2* __restrict__ epair, int m) {
    int e = blockIdx.x * 256 + threadIdx.x;
    if (e >= m) return;
    int s = src[e], d = dst[e];
    int pos = atomicAdd(&cursor[d], 1);
    epair[pos] = make_int2(s, __float_as_int(dinv[s] * dinv[d]));
}

// GEMM1: hist prologue + [n,128]@[128,128] fp32, 128x128 tile, 8x8 micro-tile,
// bf16 output. Hist atomics are independent of the matmul and drain under it;
// kernel completion guarantees cnt is final before k_scan_coop starts.
__global__ __launch_bounds__(256) void k_gemm1(
    const float* __restrict__ X, const float* __restrict__ W,
    unsigned short* __restrict__ Hb, const int* __restrict__ dst,
    int* __restrict__ cnt, int n, int m)
{
    // hist prologue (fire-and-forget atomics)
    {
        int gid = blockIdx.x * 256 + threadIdx.x;
        int gsz = gridDim.x * 256;
        for (int e = gid; e < m; e += gsz) atomicAdd(&cnt[dst[e]], 1);
    }

    __shared__ float xs[128][36];
    __shared__ float ws[32][128];
    const int t  = threadIdx.x;
    const int tx = t & 15;
    const int ty = t >> 4;
    const int r0 = blockIdx.x * 128;
    float acc[8][8] = {};

    for (int kc = 0; kc < 128; kc += 32) {
#pragma unroll
        for (int i = 0; i < 4; ++i) {
            int idx = t + i * 256;
            int row = idx >> 3;
            int q   = idx & 7;
            int r   = r0 + row;
            float4 v = make_float4(0.f, 0.f, 0.f, 0.f);
            if (r < n) v = *(const float4*)&X[(size_t)r * 128 + kc + q * 4];
            *(float4*)&xs[row][q * 4] = v;
        }
#pragma unroll
        for (int i = 0; i < 4; ++i) {
            int idx = t + i * 256;
            int kk  = idx >> 5;
            int cg2 = idx & 31;
            *(float4*)&ws[kk][cg2 * 4] = *(const float4*)&W[(size_t)(kc + kk) * 128 + cg2 * 4];
        }
        __syncthreads();
#pragma unroll
        for (int kk = 0; kk < 32; ++kk) {
            float xv[8];
#pragma unroll
            for (int i = 0; i < 8; ++i) xv[i] = xs[ty + 16 * i][kk];
            float4 w0 = *(const float4*)&ws[kk][tx * 8];
            float4 w1 = *(const float4*)&ws[kk][tx * 8 + 4];
#pragma unroll
            for (int i = 0; i < 8; ++i) {
                acc[i][0] = fmaf(xv[i], w0.x, acc[i][0]);
                acc[i][1] = fmaf(xv[i], w0.y, acc[i][1]);
                acc[i][2] = fmaf(xv[i], w0.z, acc[i][2]);
                acc[i][3] = fmaf(xv[i], w0.w, acc[i][3]);
                acc[i][4] = fmaf(xv[i], w1.x, acc[i][4]);
                acc[i][5] = fmaf(xv[i], w1.y, acc[i][5]);
                acc[i][6] = fmaf(xv[i], w1.z, acc[i][6]);
                acc[i][7] = fmaf(xv[i], w1.w, acc[i][7]);
            }
        }
        __syncthreads();
    }

#pragma unroll
    for (int i = 0; i < 8; ++i) {
        int r = r0 + ty + 16 * i;
        if (r < n) {
            ushort4 o0 = make_ushort4(f2bf(acc[i][0]), f2bf(acc[i][1]),
                                      f2bf(acc[i][2]), f2bf(acc[i][3]));
            ushort4 o1 = make_ushort4(f2bf(acc[i][4]), f2bf(acc[i][5]),
                                      f2bf(acc[i][6]), f2bf(acc[i][7]));
            *(ushort4*)&Hb[(size_t)r * 128 + tx * 8]     = o0;
            *(ushort4*)&Hb[(size_t)r * 128 + tx * 8 + 4] = o1;
        }
    }
}

// Fused layer-1 aggregation + GEMM2. 32 rows per 256-thread block.
__global__ __launch_bounds__(256) void k_agg1g2(
    const int* __restrict__ rowstart, const int2* __restrict__ epair,
    const unsigned short* __restrict__ Hb, const float* __restrict__ B1,
    const float* __restrict__ W2, const float* __restrict__ dinv,
    unsigned short* __restrict__ H3b, int n)
{
    __shared__ float tile[32][132];     // +4 pad: conflict-free column reads
    __shared__ float ws2[128 * 40];
    const int t  = threadIdx.x;
    const int r0 = blockIdx.x * 32;

#pragma unroll
    for (int i = 0; i < 20; ++i) ws2[t + i * 256] = W2[t + i * 256];

    const int lane = t & 15;
    for (int rr = t >> 4; rr < 32; rr += 16) {
        int r = r0 + rr;
        if (r < n) {
            float di = dinv[r], d2 = di * di;
            uint4 hu = *(const uint4*)&Hb[(size_t)r * 128 + lane * 8];
            float a0[8], a1[8] = {}, a2[8] = {}, a3[8] = {};
            {
                const float* bp = &B1[lane * 8];
                float h[8] = {bflo(hu.x), bfhi(hu.x), bflo(hu.y), bfhi(hu.y),
                              bflo(hu.z), bfhi(hu.z), bflo(hu.w), bfhi(hu.w)};
#pragma unroll
                for (int c = 0; c < 8; ++c) a0[c] = fmaf(h[c], d2, bp[c]);
            }
            int j  = rowstart[r];
            int j1 = rowstart[r + 1];
            for (; j + 4 <= j1; j += 4) {
                int2 p0 = epair[j], p1 = epair[j + 1], p2 = epair[j + 2], p3 = epair[j + 3];
                uint4 u0 = *(const uint4*)&Hb[(size_t)p0.x * 128 + lane * 8];
                uint4 u1 = *(const uint4*)&Hb[(size_t)p1.x * 128 + lane * 8];
                uint4 u2 = *(const uint4*)&Hb[(size_t)p2.x * 128 + lane * 8];
                uint4 u3 = *(const uint4*)&Hb[(size_t)p3.x * 128 + lane * 8];
                fma8(a0, u0, __int_as_float(p0.y));
                fma8(a1, u1, __int_as_float(p1.y));
                fma8(a2, u2, __int_as_float(p2.y));
                fma8(a3, u3, __int_as_float(p3.y));
            }
            for (; j < j1; ++j) {
                int2 pe = epair[j];
                uint4 u = *(const uint4*)&Hb[(size_t)pe.x * 128 + lane * 8];
                fma8(a0, u, __int_as_float(pe.y));
            }
            float* p = &tile[rr][lane * 8];
#pragma unroll
            for (int c = 0; c < 8; ++c)
                p[c] = fmaxf(a0[c] + a1[c] + a2[c] + a3[c], 0.f);   // fused ReLU
        }
    }
    __syncthreads();

    // matmul: each thread = 1 row x 5 cols
    int r = r0 + (t >> 3);
    if (r < n) {
        const int c0 = (t & 7) * 5;
        const float* arow = tile[t >> 3];
        float acc[5] = {};
#pragma unroll 4
        for (int kk = 0; kk < 128; ++kk) {
            float a = arow[kk];
            const float* wp = &ws2[kk * 40 + c0];
#pragma unroll
            for (int j = 0; j < 5; ++j) acc[j] = fmaf(a, wp[j], acc[j]);
        }
#pragma unroll
        for (int j = 0; j < 5; ++j)
            H3b[(size_t)r * 40 + c0 + j] = f2bf(acc[j]);
    }
}

// layer-2 aggregation: 5 lanes/row, 8 ch each (uint4 = 16B), 320-thread blocks
__global__ __launch_bounds__(320) void k_agg2(
    const int* __restrict__ rowstart, const int2* __restrict__ epair,
    const unsigned short* __restrict__ H3b, const float* __restrict__ B,
    const float* __restrict__ dinv, float* __restrict__ OUT, int n)
{
    int t = threadIdx.x;
    int r = blockIdx.x * 64 + t / 5;
    int q = t % 5;
    if (r >= n) return;
    float di = dinv[r], d2 = di * di;
    uint4 hu = *(const uint4*)&H3b[(size_t)r * 40 + q * 8];
    float a0[8], a1[8] = {}, a2[8] = {}, a3[8] = {};
    {
        const float* bp = &B[q * 8];
        float h[8] = {bflo(hu.x), bfhi(hu.x), bflo(hu.y), bfhi(hu.y),
                      bflo(hu.z), bfhi(hu.z), bflo(hu.w), bfhi(hu.w)};
#pragma unroll
        for (int c = 0; c < 8; ++c) a0[c] = fmaf(h[c], d2, bp[c]);
    }
    int j  = rowstart[r];
    int j1 = rowstart[r + 1];
    for (; j + 4 <= j1; j += 4) {
        int2 p0 = epair[j], p1 = epair[j + 1], p2 = epair[j + 2], p3 = epair[j + 3];
        uint4 u0 = *(const uint4*)&H3b[(size_t)p0.x * 40 + q * 8];
        uint4 u1 = *(const uint4*)&H3b[(size_t)p1.x * 40 + q * 8];
        uint4 u2 = *(const uint4*)&H3b[(size_t)p2.x * 40 + q * 8];
        uint4 u3 = *(const uint4*)&H3b[(size_t)p3.x * 40 + q * 8];
        fma8(a0, u0, __int_as_float(p0.y));
        fma8(a1, u1, __int_as_float(p1.y));
        fma8(a2, u2, __int_as_float(p2.y));
        fma8(a3, u3, __int_as_float(p3.y));
    }
    for (; j < j1; ++j) {
        int2 pe = epair[j];
        uint4 u = *(const uint4*)&H3b[(size_t)pe.x * 40 + q * 8];
        fma8(a0, u, __int_as_float(pe.y));
    }
    float o[8];
#pragma unroll
    for (int c = 0; c < 8; ++c) o[c] = a0[c] + a1[c] + a2[c] + a3[c];
    float* p = &OUT[(size_t)r * 40 + q * 8];
    *(float4*)(p)     = make_float4(o[0], o[1], o[2], o[3]);
    *(float4*)(p + 4) = make_float4(o[4], o[5], o[6], o[7]);
}

extern "C" void kernel_launch(void* const* d_in, const int* in_sizes, int n_in,
                              void* d_out, int out_size, void* d_ws, size_t ws_size,
                              hipStream_t stream) {
    const float* x  = (const float*)d_in[0];
    const int*   ei = (const int*)d_in[1];
    const float* W1 = (const float*)d_in[2];
    const float* b1 = (const float*)d_in[3];
    const float* W2 = (const float*)d_in[4];
    const float* b2 = (const float*)d_in[5];
    float* out = (float*)d_out;

    const int n = in_sizes[0] / 128;     // 50000
    const int m = in_sizes[1] / 2;       // 600000
    const int* src = ei;
    const int* dst = ei + m;
    const int nb = (n + 255) / 256;      // 196

    char* p = (char*)d_ws;
    auto take = [&](size_t bytes) { char* q = p; p += (bytes + 255) & ~(size_t)255; return q; };
    int*   cnt      = (int*)take(sizeof(int) * n);
    int*   rowstart = (int*)take(sizeof(int) * (n + 1));
    int*   cursor   = (int*)take(sizeof(int) * n);
    int*   bsum     = (int*)take(sizeof(int) * 256);
    int*   boff     = (int*)take(sizeof(int) * 256);
    int2*  epair    = (int2*)take(sizeof(int2) * m);
    float* dinv     = (float*)take(sizeof(float) * n);
    unsigned short* H1b = (unsigned short*)take(sizeof(short) * (size_t)n * 128);
    unsigned short* H3b = (unsigned short*)take(sizeof(short) * (size_t)n * 40);

    k_zero <<<nb, 256, 0, stream>>>(cnt, n);
    k_gemm1<<<(n + 127) / 128, 256, 0, stream>>>(x, W1, H1b, dst, cnt, n, m);

    {
        // cooperative scan: exactly nb (=196) blocks, trivially co-resident
        int nn = n, mm = m;
        void* args[] = {(void*)&cnt, (void*)&rowstart, (void*)&cursor, (void*)&dinv,
                        (void*)&bsum, (void*)&boff, (void*)&nn, (void*)&mm};
        hipLaunchCooperativeKernel((void*)k_scan_coop, dim3(nb), dim3(256), args, 0, stream);
    }

    k_scatter<<<(m + 255) / 256, 256, 0, stream>>>(src, dst, dinv, cursor, epair, m);
    k_agg1g2 <<<(n + 31) / 32, 256, 0, stream>>>(rowstart, epair, H1b, b1, W2, dinv, H3b, n);
    k_agg2   <<<(n + 63) / 64, 320, 0, stream>>>(rowstart, epair, H3b, b2, dinv, out, n);
}

// Round 9
// 157.994 us; speedup vs baseline: 1.8728x; 1.3488x over previous
//
#include <hip/hip_runtime.h>

// ---------------------------------------------------------------------------
// GCN 2-layer forward. r6 pipeline (proven) + MFMA-bf16 gemm1.
//   k_zero:    cnt = 0  (+ tail blocks: WT[c][k] = bf16(W1[k][c]))
//   k_hist:    cnt[dst]++ (int atomics)
//   scan x3:   rowstart = exscan(cnt), cursor init, dinv = rsqrt(cnt+1)
//   k_scatter: CSR (src,norm) int2 pairs grouped by dst
//   k_gemm1:   H1b = bf16(x@W1)  -- MFMA 16x16x32, A from global fp32->bf16,
//              B from L2-resident WT, no LDS
//   k_agg1:    AGG = relu(b1 + H1b*dinv^2 + gather(H1b))  fp32
//   k_gemm2:   H3b = bf16(AGG@W2)
//   k_agg2:    OUT = b2 + H3b*dinv^2 + gather(H3b)
// ---------------------------------------------------------------------------

typedef __attribute__((ext_vector_type(8))) short bf16x8;
typedef __attribute__((ext_vector_type(4))) float f32x4;

__device__ inline unsigned short f2bf(float x) {
    unsigned u = __float_as_uint(x);
    unsigned r = (u + 0x7FFFu + ((u >> 16) & 1u)) >> 16;   // round-nearest-even
    return (unsigned short)r;
}
__device__ inline float bflo(unsigned u) { return __uint_as_float(u << 16); }
__device__ inline float bfhi(unsigned u) { return __uint_as_float(u & 0xFFFF0000u); }

__device__ inline void fma8(float* acc, uint4 uv, float wt) {
    acc[0] = fmaf(bflo(uv.x), wt, acc[0]);
    acc[1] = fmaf(bfhi(uv.x), wt, acc[1]);
    acc[2] = fmaf(bflo(uv.y), wt, acc[2]);
    acc[3] = fmaf(bfhi(uv.y), wt, acc[3]);
    acc[4] = fmaf(bflo(uv.z), wt, acc[4]);
    acc[5] = fmaf(bfhi(uv.z), wt, acc[5]);
    acc[6] = fmaf(bflo(uv.w), wt, acc[6]);
    acc[7] = fmaf(bfhi(uv.w), wt, acc[7]);
}

// blocks [0,nb): zero cnt. blocks [nb, nb+16): WT[c][k] = bf16(W1[k][c]).
__global__ __launch_bounds__(256) void k_zero(int* __restrict__ cnt,
                                              const float* __restrict__ W1,
                                              unsigned short* __restrict__ WT,
                                              int n, int nb) {
    int b = blockIdx.x;
    if (b < nb) {
        int i = b * 256 + threadIdx.x;
        if (i < n) cnt[i] = 0;
    } else {
        int idx = (b - nb) * 256 + threadIdx.x;     // 0..4095
        for (int i = idx; i < 128 * 128; i += 4096) {
            int k = i >> 7, c = i & 127;
            WT[c * 128 + k] = f2bf(W1[i]);
        }
    }
}

__global__ __launch_bounds__(256) void k_hist(const int* __restrict__ dst,
                                              int* __restrict__ cnt, int m) {
    int i = blockIdx.x * 256 + threadIdx.x;
    if (i < m) atomicAdd(&cnt[dst[i]], 1);
}

__global__ __launch_bounds__(256) void k_scan_local(const int* __restrict__ cnt,
                                                    int* __restrict__ rowstart,
                                                    int* __restrict__ bsum,
                                                    float* __restrict__ dinv, int n) {
    __shared__ int s[256];
    int t = threadIdx.x;
    int i = blockIdx.x * 256 + t;
    int v = (i < n) ? cnt[i] : 0;
    if (i < n) dinv[i] = rsqrtf((float)v + 1.0f);
    s[t] = v;
    __syncthreads();
#pragma unroll
    for (int off = 1; off < 256; off <<= 1) {
        int x = s[t];
        if (t >= off) x += s[t - off];
        __syncthreads();
        s[t] = x;
        __syncthreads();
    }
    if (i < n) rowstart[i] = s[t] - v;
    if (t == 255) bsum[blockIdx.x] = s[255];
}

__global__ __launch_bounds__(256) void k_scan_bsum(int* __restrict__ bsum,
                                                   int* __restrict__ boff, int nb) {
    __shared__ int s[256];
    int t = threadIdx.x;
    int v = (t < nb) ? bsum[t] : 0;
    s[t] = v;
    __syncthreads();
#pragma unroll
    for (int off = 1; off < 256; off <<= 1) {
        int x = s[t];
        if (t >= off) x += s[t - off];
        __syncthreads();
        s[t] = x;
        __syncthreads();
    }
    if (t < nb) boff[t] = s[t] - v;
}

__global__ __launch_bounds__(256) void k_scan_add(int* __restrict__ rowstart,
                                                  const int* __restrict__ boff,
                                                  int* __restrict__ cursor, int n, int m) {
    int i = blockIdx.x * 256 + threadIdx.x;
    if (i < n) {
        int v = rowstart[i] + boff[blockIdx.x];
        rowstart[i] = v;
        cursor[i]   = v;
    }
    if (i == 0) rowstart[n] = m;
}

__global__ __launch_bounds__(256) void k_scatter(const int* __restrict__ src,
                                                 const int* __restrict__ dst,
                                                 const float* __restrict__ dinv,
                                                 int* __restrict__ cursor,
                                                 int2* __restrict__ epair, int m) {
    int e = blockIdx.x * 256 + threadIdx.x;
    if (e >= m) return;
    int s = src[e], d = dst[e];
    int pos = atomicAdd(&cursor[d], 1);
    epair[pos] = make_int2(s, __float_as_int(dinv[s] * dinv[d]));
}

// GEMM1 via MFMA bf16: 64 rows/block, 4 waves, each wave 16 rows x 128 cols.
// A frag: lane holds x[rw + (l&15)][kk*32 + (l>>4)*8 + e], e=0..7 (fp32->bf16).
// B frag: lane holds W1[kk*32 + (l>>4)*8 + e][16j + (l&15)] = 16B load from WT.
// D: col = 16j + (l&15), row = rw + (l>>4)*4 + reg   [m89-verified mapping].
__global__ __launch_bounds__(256) void k_gemm1(
    const float* __restrict__ X, const unsigned short* __restrict__ WT,
    unsigned short* __restrict__ Hb, int n)
{
    const int l  = threadIdx.x & 63;
    const int w  = threadIdx.x >> 6;
    const int rw = blockIdx.x * 64 + w * 16;
    const int lr = l & 15;
    const int kq = l >> 4;                       // k-quarter AND output row-group

    int arow = rw + lr;
    if (arow > n - 1) arow = n - 1;              // clamp: garbage rows never written
    const float* xp = X + (size_t)arow * 128 + kq * 8;

    f32x4 acc[8];
#pragma unroll
    for (int j = 0; j < 8; ++j) acc[j] = (f32x4){0.f, 0.f, 0.f, 0.f};

#pragma unroll
    for (int kk = 0; kk < 4; ++kk) {
        float4 v0 = *(const float4*)(xp + kk * 32);
        float4 v1 = *(const float4*)(xp + kk * 32 + 4);
        bf16x8 a;
        a[0] = (short)f2bf(v0.x); a[1] = (short)f2bf(v0.y);
        a[2] = (short)f2bf(v0.z); a[3] = (short)f2bf(v0.w);
        a[4] = (short)f2bf(v1.x); a[5] = (short)f2bf(v1.y);
        a[6] = (short)f2bf(v1.z); a[7] = (short)f2bf(v1.w);
#pragma unroll
        for (int j = 0; j < 8; ++j) {
            const bf16x8 b = *(const bf16x8*)(WT + (size_t)(j * 16 + lr) * 128 + kk * 32 + kq * 8);
            acc[j] = __builtin_amdgcn_mfma_f32_16x16x32_bf16(a, b, acc[j], 0, 0, 0);
        }
    }

#pragma unroll
    for (int j = 0; j < 8; ++j) {
        int col = j * 16 + lr;
#pragma unroll
        for (int r4 = 0; r4 < 4; ++r4) {
            int rr = rw + kq * 4 + r4;
            if (rr < n) Hb[(size_t)rr * 128 + col] = f2bf(acc[j][r4]);
        }
    }
}

// layer-1 aggregation: 16 lanes/row, 8 ch each (uint4 = 16B), 4-way unrolled, ReLU
__global__ __launch_bounds__(256) void k_agg1(
    const int* __restrict__ rowstart, const int2* __restrict__ epair,
    const unsigned short* __restrict__ Hb, const float* __restrict__ B,
    const float* __restrict__ dinv, float* __restrict__ AGG, int n)
{
    int t = threadIdx.x;
    int lane = t & 15;
    int r = blockIdx.x * 16 + (t >> 4);
    if (r >= n) return;
    float di = dinv[r], d2 = di * di;
    uint4 hu = *(const uint4*)&Hb[(size_t)r * 128 + lane * 8];
    float a0[8], a1[8] = {}, a2[8] = {}, a3[8] = {};
    {
        const float* bp = &B[lane * 8];
        float h[8] = {bflo(hu.x), bfhi(hu.x), bflo(hu.y), bfhi(hu.y),
                      bflo(hu.z), bfhi(hu.z), bflo(hu.w), bfhi(hu.w)};
#pragma unroll
        for (int c = 0; c < 8; ++c) a0[c] = fmaf(h[c], d2, bp[c]);
    }
    int j  = rowstart[r];
    int j1 = rowstart[r + 1];
    for (; j + 4 <= j1; j += 4) {
        int2 p0 = epair[j], p1 = epair[j + 1], p2 = epair[j + 2], p3 = epair[j + 3];
        uint4 u0 = *(const uint4*)&Hb[(size_t)p0.x * 128 + lane * 8];
        uint4 u1 = *(const uint4*)&Hb[(size_t)p1.x * 128 + lane * 8];
        uint4 u2 = *(const uint4*)&Hb[(size_t)p2.x * 128 + lane * 8];
        uint4 u3 = *(const uint4*)&Hb[(size_t)p3.x * 128 + lane * 8];
        fma8(a0, u0, __int_as_float(p0.y));
        fma8(a1, u1, __int_as_float(p1.y));
        fma8(a2, u2, __int_as_float(p2.y));
        fma8(a3, u3, __int_as_float(p3.y));
    }
    for (; j < j1; ++j) {
        int2 pe = epair[j];
        uint4 u = *(const uint4*)&Hb[(size_t)pe.x * 128 + lane * 8];
        fma8(a0, u, __int_as_float(pe.y));
    }
    float o[8];
#pragma unroll
    for (int c = 0; c < 8; ++c)
        o[c] = fmaxf(a0[c] + a1[c] + a2[c] + a3[c], 0.f);     // fused ReLU
    float* p = &AGG[(size_t)r * 128 + lane * 8];
    *(float4*)(p)     = make_float4(o[0], o[1], o[2], o[3]);
    *(float4*)(p + 4) = make_float4(o[4], o[5], o[6], o[7]);
}

// GEMM2: AGG[n,128] fp32 @ [128,40] -> H3 bf16
__global__ __launch_bounds__(256) void k_gemm2(
    const float* __restrict__ X, const float* __restrict__ W,
    unsigned short* __restrict__ H3b, int n)
{
    __shared__ float xs[128][17];
    __shared__ float ws[128 * 40];
    const int t  = threadIdx.x;
    const int tx = t & 7;
    const int ty = t >> 3;
    const int r0 = blockIdx.x * 128;

#pragma unroll
    for (int i = 0; i < 20; ++i) ws[t + i * 256] = W[t + i * 256];

    float acc[4][5] = {};
    for (int kc = 0; kc < 128; kc += 16) {
#pragma unroll
        for (int i = 0; i < 2; ++i) {
            int idx = t + i * 256;
            int row = idx >> 2;
            int q   = idx & 3;
            int r   = r0 + row;
            float4 v = make_float4(0.f, 0.f, 0.f, 0.f);
            if (r < n) v = *(const float4*)&X[(size_t)r * 128 + kc + q * 4];
            float* p = &xs[row][q * 4];
            p[0] = v.x; p[1] = v.y; p[2] = v.z; p[3] = v.w;
        }
        __syncthreads();
#pragma unroll
        for (int kk = 0; kk < 16; ++kk) {
            float wv[5];
            const float* wp = &ws[(kc + kk) * 40 + tx * 5];
#pragma unroll
            for (int j = 0; j < 5; ++j) wv[j] = wp[j];
#pragma unroll
            for (int i = 0; i < 4; ++i) {
                float xv = xs[ty * 4 + i][kk];
#pragma unroll
                for (int j = 0; j < 5; ++j) acc[i][j] = fmaf(xv, wv[j], acc[i][j]);
            }
        }
        __syncthreads();
    }

#pragma unroll
    for (int i = 0; i < 4; ++i) {
        int r = r0 + ty * 4 + i;
        if (r < n) {
#pragma unroll
            for (int j = 0; j < 5; ++j)
                H3b[(size_t)r * 40 + tx * 5 + j] = f2bf(acc[i][j]);
        }
    }
}

// layer-2 aggregation: 5 lanes/row, 8 ch each (uint4 = 16B), 320-thread blocks
__global__ __launch_bounds__(320) void k_agg2(
    const int* __restrict__ rowstart, const int2* __restrict__ epair,
    const unsigned short* __restrict__ H3b, const float* __restrict__ B,
    const float* __restrict__ dinv, float* __restrict__ OUT, int n)
{
    int t = threadIdx.x;
    int r = blockIdx.x * 64 + t / 5;
    int q = t % 5;
    if (r >= n) return;
    float di = dinv[r], d2 = di * di;
    uint4 hu = *(const uint4*)&H3b[(size_t)r * 40 + q * 8];
    float a0[8], a1[8] = {}, a2[8] = {}, a3[8] = {};
    {
        const float* bp = &B[q * 8];
        float h[8] = {bflo(hu.x), bfhi(hu.x), bflo(hu.y), bfhi(hu.y),
                      bflo(hu.z), bfhi(hu.z), bflo(hu.w), bfhi(hu.w)};
#pragma unroll
        for (int c = 0; c < 8; ++c) a0[c] = fmaf(h[c], d2, bp[c]);
    }
    int j  = rowstart[r];
    int j1 = rowstart[r + 1];
    for (; j + 4 <= j1; j += 4) {
        int2 p0 = epair[j], p1 = epair[j + 1], p2 = epair[j + 2], p3 = epair[j + 3];
        uint4 u0 = *(const uint4*)&H3b[(size_t)p0.x * 40 + q * 8];
        uint4 u1 = *(const uint4*)&H3b[(size_t)p1.x * 40 + q * 8];
        uint4 u2 = *(const uint4*)&H3b[(size_t)p2.x * 40 + q * 8];
        uint4 u3 = *(const uint4*)&H3b[(size_t)p3.x * 40 + q * 8];
        fma8(a0, u0, __int_as_float(p0.y));
        fma8(a1, u1, __int_as_float(p1.y));
        fma8(a2, u2, __int_as_float(p2.y));
        fma8(a3, u3, __int_as_float(p3.y));
    }
    for (; j < j1; ++j) {
        int2 pe = epair[j];
        uint4 u = *(const uint4*)&H3b[(size_t)pe.x * 40 + q * 8];
        fma8(a0, u, __int_as_float(pe.y));
    }
    float o[8];
#pragma unroll
    for (int c = 0; c < 8; ++c) o[c] = a0[c] + a1[c] + a2[c] + a3[c];
    float* p = &OUT[(size_t)r * 40 + q * 8];
    *(float4*)(p)     = make_float4(o[0], o[1], o[2], o[3]);
    *(float4*)(p + 4) = make_float4(o[4], o[5], o[6], o[7]);
}

extern "C" void kernel_launch(void* const* d_in, const int* in_sizes, int n_in,
                              void* d_out, int out_size, void* d_ws, size_t ws_size,
                              hipStream_t stream) {
    const float* x  = (const float*)d_in[0];
    const int*   ei = (const int*)d_in[1];
    const float* W1 = (const float*)d_in[2];
    const float* b1 = (const float*)d_in[3];
    const float* W2 = (const float*)d_in[4];
    const float* b2 = (const float*)d_in[5];
    float* out = (float*)d_out;

    const int n = in_sizes[0] / 128;     // 50000
    const int m = in_sizes[1] / 2;       // 600000
    const int* src = ei;
    const int* dst = ei + m;
    const int nb = (n + 255) / 256;      // 196

    char* p = (char*)d_ws;
    auto take = [&](size_t bytes) { char* q = p; p += (bytes + 255) & ~(size_t)255; return q; };
    int*   cnt      = (int*)take(sizeof(int) * n);
    int*   rowstart = (int*)take(sizeof(int) * (n + 1));
    int*   cursor   = (int*)take(sizeof(int) * n);
    int*   bsum     = (int*)take(sizeof(int) * 256);
    int*   boff     = (int*)take(sizeof(int) * 256);
    int2*  epair    = (int2*)take(sizeof(int2) * m);
    float* dinv     = (float*)take(sizeof(float) * n);
    unsigned short* WT  = (unsigned short*)take(sizeof(short) * 128 * 128);
    unsigned short* H1b = (unsigned short*)take(sizeof(short) * (size_t)n * 128);
    float* AGG      = (float*)take(sizeof(float) * (size_t)n * 128);
    unsigned short* H3b = H1b;           // alias: H1b dead after k_agg1

    k_zero      <<<nb + 16, 256, 0, stream>>>(cnt, W1, WT, n, nb);
    k_hist      <<<(m + 255) / 256, 256, 0, stream>>>(dst, cnt, m);
    k_scan_local<<<nb, 256, 0, stream>>>(cnt, rowstart, bsum, dinv, n);
    k_scan_bsum <<<1, 256, 0, stream>>>(bsum, boff, nb);
    k_scan_add  <<<nb, 256, 0, stream>>>(rowstart, boff, cursor, n, m);
    k_scatter   <<<(m + 255) / 256, 256, 0, stream>>>(src, dst, dinv, cursor, epair, m);

    k_gemm1<<<(n + 63) / 64, 256, 0, stream>>>(x, WT, H1b, n);
    k_agg1 <<<(n + 15) / 16, 256, 0, stream>>>(rowstart, epair, H1b, b1, dinv, AGG, n);
    k_gemm2<<<(n + 127) / 128, 256, 0, stream>>>(AGG, W2, H3b, n);
    k_agg2 <<<(n + 63) / 64, 320, 0, stream>>>(rowstart, epair, H3b, b2, dinv, out, n);
}

// Round 10
// 148.137 us; speedup vs baseline: 1.9974x; 1.0665x over previous
//
#include <hip/hip_runtime.h>

// ---------------------------------------------------------------------------
// GCN 2-layer forward. 9 launches:
//   k_zero:    cnt=0; tail blocks: WT = bf16(W1^T) [128][128], WT2 = bf16(W2^T)
//              padded to [48][128] (cols 40..47 zero)
//   k_hist:    cnt[dst]++ (int atomics)
//   k_scan_local: block-local exscan + dinv
//   k_scan_add:   each block scans bsum in LDS, globalizes, inits cursor
//   k_scatter: CSR (src,norm) int2 pairs grouped by dst
//   k_gemm1:   H1b = bf16(x@W1)   MFMA 16x16x32, LDS-free
//   k_agg1:    AGGb = bf16(relu(b1 + H1b*dinv^2 + gather(H1b)))
//   k_gemm2:   H3b = bf16(AGGb@W2) MFMA 16x16x32, LDS-free
//   k_agg2:    OUT = b2 + H3b*dinv^2 + gather(H3b)
// ---------------------------------------------------------------------------

typedef __attribute__((ext_vector_type(8))) short bf16x8;
typedef __attribute__((ext_vector_type(4))) float f32x4;

__device__ inline unsigned short f2bf(float x) {
    unsigned u = __float_as_uint(x);
    unsigned r = (u + 0x7FFFu + ((u >> 16) & 1u)) >> 16;   // round-nearest-even
    return (unsigned short)r;
}
__device__ inline float bflo(unsigned u) { return __uint_as_float(u << 16); }
__device__ inline float bfhi(unsigned u) { return __uint_as_float(u & 0xFFFF0000u); }

__device__ inline void fma8(float* acc, uint4 uv, float wt) {
    acc[0] = fmaf(bflo(uv.x), wt, acc[0]);
    acc[1] = fmaf(bfhi(uv.x), wt, acc[1]);
    acc[2] = fmaf(bflo(uv.y), wt, acc[2]);
    acc[3] = fmaf(bfhi(uv.y), wt, acc[3]);
    acc[4] = fmaf(bflo(uv.z), wt, acc[4]);
    acc[5] = fmaf(bfhi(uv.z), wt, acc[5]);
    acc[6] = fmaf(bflo(uv.w), wt, acc[6]);
    acc[7] = fmaf(bfhi(uv.w), wt, acc[7]);
}

// blocks [0,nb): zero cnt. [nb,nb+16): WT = W1^T. [nb+16,nb+24): WT2 = W2^T pad48.
__global__ __launch_bounds__(256) void k_zero(int* __restrict__ cnt,
                                              const float* __restrict__ W1,
                                              const float* __restrict__ W2,
                                              unsigned short* __restrict__ WT,
                                              unsigned short* __restrict__ WT2,
                                              int n, int nb) {
    int b = blockIdx.x;
    if (b < nb) {
        int i = b * 256 + threadIdx.x;
        if (i < n) cnt[i] = 0;
    } else if (b < nb + 16) {
        int idx = (b - nb) * 256 + threadIdx.x;        // 0..4095
        for (int i = idx; i < 128 * 128; i += 4096) {
            int k = i >> 7, c = i & 127;
            WT[c * 128 + k] = f2bf(W1[i]);
        }
    } else {
        int idx = (b - nb - 16) * 256 + threadIdx.x;   // 0..2047
        for (int i = idx; i < 48 * 128; i += 2048) {
            int c = i >> 7, k = i & 127;
            WT2[i] = (c < 40) ? f2bf(W2[k * 40 + c]) : (unsigned short)0;
        }
    }
}

__global__ __launch_bounds__(256) void k_hist(const int* __restrict__ dst,
                                              int* __restrict__ cnt, int m) {
    int i = blockIdx.x * 256 + threadIdx.x;
    if (i < m) atomicAdd(&cnt[dst[i]], 1);
}

__global__ __launch_bounds__(256) void k_scan_local(const int* __restrict__ cnt,
                                                    int* __restrict__ rowstart,
                                                    int* __restrict__ bsum,
                                                    float* __restrict__ dinv, int n) {
    __shared__ int s[256];
    int t = threadIdx.x;
    int i = blockIdx.x * 256 + t;
    int v = (i < n) ? cnt[i] : 0;
    if (i < n) dinv[i] = rsqrtf((float)v + 1.0f);
    s[t] = v;
    __syncthreads();
#pragma unroll
    for (int off = 1; off < 256; off <<= 1) {
        int x = s[t];
        if (t >= off) x += s[t - off];
        __syncthreads();
        s[t] = x;
        __syncthreads();
    }
    if (i < n) rowstart[i] = s[t] - v;        // block-local exclusive
    if (t == 255) bsum[blockIdx.x] = s[255];
}

// each block re-scans all block sums in LDS (nb <= 256), then globalizes
__global__ __launch_bounds__(256) void k_scan_add(int* __restrict__ rowstart,
                                                  const int* __restrict__ bsum,
                                                  int* __restrict__ cursor,
                                                  int n, int m, int nb) {
    __shared__ int s[256];
    int t = threadIdx.x;
    int b = blockIdx.x;
    s[t] = (t < nb) ? bsum[t] : 0;
    __syncthreads();
#pragma unroll
    for (int off = 1; off < 256; off <<= 1) {
        int x = s[t];
        if (t >= off) x += s[t - off];
        __syncthreads();
        s[t] = x;
        __syncthreads();
    }
    int excl = (b > 0) ? s[b - 1] : 0;        // sum of bsum[0..b)
    int i = b * 256 + t;
    if (i < n) {
        int v = rowstart[i] + excl;
        rowstart[i] = v;
        cursor[i]   = v;
    }
    if (i == 0) rowstart[n] = m;
}

__global__ __launch_bounds__(256) void k_scatter(const int* __restrict__ src,
                                                 const int* __restrict__ dst,
                                                 const float* __restrict__ dinv,
                                                 int* __restrict__ cursor,
                                                 int2* __restrict__ epair, int m) {
    int e = blockIdx.x * 256 + threadIdx.x;
    if (e >= m) return;
    int s = src[e], d = dst[e];
    int pos = atomicAdd(&cursor[d], 1);
    epair[pos] = make_int2(s, __float_as_int(dinv[s] * dinv[d]));
}

// GEMM1 via MFMA bf16: 64 rows/block, 4 waves, each wave 16 rows x 128 cols.
__global__ __launch_bounds__(256) void k_gemm1(
    const float* __restrict__ X, const unsigned short* __restrict__ WT,
    unsigned short* __restrict__ Hb, int n)
{
    const int l  = threadIdx.x & 63;
    const int w  = threadIdx.x >> 6;
    const int rw = blockIdx.x * 64 + w * 16;
    const int lr = l & 15;
    const int kq = l >> 4;

    int arow = rw + lr;
    if (arow > n - 1) arow = n - 1;              // clamp: garbage rows never written
    const float* xp = X + (size_t)arow * 128 + kq * 8;

    f32x4 acc[8];
#pragma unroll
    for (int j = 0; j < 8; ++j) acc[j] = (f32x4){0.f, 0.f, 0.f, 0.f};

#pragma unroll
    for (int kk = 0; kk < 4; ++kk) {
        float4 v0 = *(const float4*)(xp + kk * 32);
        float4 v1 = *(const float4*)(xp + kk * 32 + 4);
        bf16x8 a;
        a[0] = (short)f2bf(v0.x); a[1] = (short)f2bf(v0.y);
        a[2] = (short)f2bf(v0.z); a[3] = (short)f2bf(v0.w);
        a[4] = (short)f2bf(v1.x); a[5] = (short)f2bf(v1.y);
        a[6] = (short)f2bf(v1.z); a[7] = (short)f2bf(v1.w);
#pragma unroll
        for (int j = 0; j < 8; ++j) {
            const bf16x8 b = *(const bf16x8*)(WT + (size_t)(j * 16 + lr) * 128 + kk * 32 + kq * 8);
            acc[j] = __builtin_amdgcn_mfma_f32_16x16x32_bf16(a, b, acc[j], 0, 0, 0);
        }
    }

#pragma unroll
    for (int j = 0; j < 8; ++j) {
        int col = j * 16 + lr;
#pragma unroll
        for (int r4 = 0; r4 < 4; ++r4) {
            int rr = rw + kq * 4 + r4;
            if (rr < n) Hb[(size_t)rr * 128 + col] = f2bf(acc[j][r4]);
        }
    }
}

// layer-1 aggregation: 16 lanes/row, 8 ch each, 4-way unrolled, ReLU, bf16 out
__global__ __launch_bounds__(256) void k_agg1(
    const int* __restrict__ rowstart, const int2* __restrict__ epair,
    const unsigned short* __restrict__ Hb, const float* __restrict__ B,
    const float* __restrict__ dinv, unsigned short* __restrict__ AGGb, int n)
{
    int t = threadIdx.x;
    int lane = t & 15;
    int r = blockIdx.x * 16 + (t >> 4);
    if (r >= n) return;
    float di = dinv[r], d2 = di * di;
    uint4 hu = *(const uint4*)&Hb[(size_t)r * 128 + lane * 8];
    float a0[8], a1[8] = {}, a2[8] = {}, a3[8] = {};
    {
        const float* bp = &B[lane * 8];
        float h[8] = {bflo(hu.x), bfhi(hu.x), bflo(hu.y), bfhi(hu.y),
                      bflo(hu.z), bfhi(hu.z), bflo(hu.w), bfhi(hu.w)};
#pragma unroll
        for (int c = 0; c < 8; ++c) a0[c] = fmaf(h[c], d2, bp[c]);
    }
    int j  = rowstart[r];
    int j1 = rowstart[r + 1];
    for (; j + 4 <= j1; j += 4) {
        int2 p0 = epair[j], p1 = epair[j + 1], p2 = epair[j + 2], p3 = epair[j + 3];
        uint4 u0 = *(const uint4*)&Hb[(size_t)p0.x * 128 + lane * 8];
        uint4 u1 = *(const uint4*)&Hb[(size_t)p1.x * 128 + lane * 8];
        uint4 u2 = *(const uint4*)&Hb[(size_t)p2.x * 128 + lane * 8];
        uint4 u3 = *(const uint4*)&Hb[(size_t)p3.x * 128 + lane * 8];
        fma8(a0, u0, __int_as_float(p0.y));
        fma8(a1, u1, __int_as_float(p1.y));
        fma8(a2, u2, __int_as_float(p2.y));
        fma8(a3, u3, __int_as_float(p3.y));
    }
    for (; j < j1; ++j) {
        int2 pe = epair[j];
        uint4 u = *(const uint4*)&Hb[(size_t)pe.x * 128 + lane * 8];
        fma8(a0, u, __int_as_float(pe.y));
    }
    unsigned o[4];
#pragma unroll
    for (int c = 0; c < 4; ++c) {
        float lo = fmaxf(a0[2*c]   + a1[2*c]   + a2[2*c]   + a3[2*c],   0.f);
        float hi = fmaxf(a0[2*c+1] + a1[2*c+1] + a2[2*c+1] + a3[2*c+1], 0.f);
        o[c] = (unsigned)f2bf(lo) | ((unsigned)f2bf(hi) << 16);
    }
    *(uint4*)&AGGb[(size_t)r * 128 + lane * 8] = make_uint4(o[0], o[1], o[2], o[3]);
}

// GEMM2 via MFMA bf16: AGGb[n,128] @ W2 -> H3b[n,40]. 64 rows/block, 4 waves.
// 3 column tiles of 16 (cols 40..47 are zero-padded in WT2, never stored).
__global__ __launch_bounds__(256) void k_gemm2(
    const unsigned short* __restrict__ AGGb, const unsigned short* __restrict__ WT2,
    unsigned short* __restrict__ H3b, int n)
{
    const int l  = threadIdx.x & 63;
    const int w  = threadIdx.x >> 6;
    const int rw = blockIdx.x * 64 + w * 16;
    const int lr = l & 15;
    const int kq = l >> 4;

    int arow = rw + lr;
    if (arow > n - 1) arow = n - 1;
    const unsigned short* ap = AGGb + (size_t)arow * 128 + kq * 8;

    f32x4 acc[3];
#pragma unroll
    for (int j = 0; j < 3; ++j) acc[j] = (f32x4){0.f, 0.f, 0.f, 0.f};

#pragma unroll
    for (int kk = 0; kk < 4; ++kk) {
        const bf16x8 a = *(const bf16x8*)(ap + kk * 32);
#pragma unroll
        for (int j = 0; j < 3; ++j) {
            const bf16x8 b = *(const bf16x8*)(WT2 + (size_t)(j * 16 + lr) * 128 + kk * 32 + kq * 8);
            acc[j] = __builtin_amdgcn_mfma_f32_16x16x32_bf16(a, b, acc[j], 0, 0, 0);
        }
    }

#pragma unroll
    for (int j = 0; j < 3; ++j) {
        int col = j * 16 + lr;
        if (col < 40) {
#pragma unroll
            for (int r4 = 0; r4 < 4; ++r4) {
                int rr = rw + kq * 4 + r4;
                if (rr < n) H3b[(size_t)rr * 40 + col] = f2bf(acc[j][r4]);
            }
        }
    }
}

// layer-2 aggregation: 5 lanes/row, 8 ch each (uint4 = 16B), 320-thread blocks
__global__ __launch_bounds__(320) void k_agg2(
    const int* __restrict__ rowstart, const int2* __restrict__ epair,
    const unsigned short* __restrict__ H3b, const float* __restrict__ B,
    const float* __restrict__ dinv, float* __restrict__ OUT, int n)
{
    int t = threadIdx.x;
    int r = blockIdx.x * 64 + t / 5;
    int q = t % 5;
    if (r >= n) return;
    float di = dinv[r], d2 = di * di;
    uint4 hu = *(const uint4*)&H3b[(size_t)r * 40 + q * 8];
    float a0[8], a1[8] = {}, a2[8] = {}, a3[8] = {};
    {
        const float* bp = &B[q * 8];
        float h[8] = {bflo(hu.x), bfhi(hu.x), bflo(hu.y), bfhi(hu.y),
                      bflo(hu.z), bfhi(hu.z), bflo(hu.w), bfhi(hu.w)};
#pragma unroll
        for (int c = 0; c < 8; ++c) a0[c] = fmaf(h[c], d2, bp[c]);
    }
    int j  = rowstart[r];
    int j1 = rowstart[r + 1];
    for (; j + 4 <= j1; j += 4) {
        int2 p0 = epair[j], p1 = epair[j + 1], p2 = epair[j + 2], p3 = epair[j + 3];
        uint4 u0 = *(const uint4*)&H3b[(size_t)p0.x * 40 + q * 8];
        uint4 u1 = *(const uint4*)&H3b[(size_t)p1.x * 40 + q * 8];
        uint4 u2 = *(const uint4*)&H3b[(size_t)p2.x * 40 + q * 8];
        uint4 u3 = *(const uint4*)&H3b[(size_t)p3.x * 40 + q * 8];
        fma8(a0, u0, __int_as_float(p0.y));
        fma8(a1, u1, __int_as_float(p1.y));
        fma8(a2, u2, __int_as_float(p2.y));
        fma8(a3, u3, __int_as_float(p3.y));
    }
    for (; j < j1; ++j) {
        int2 pe = epair[j];
        uint4 u = *(const uint4*)&H3b[(size_t)pe.x * 40 + q * 8];
        fma8(a0, u, __int_as_float(pe.y));
    }
    float o[8];
#pragma unroll
    for (int c = 0; c < 8; ++c) o[c] = a0[c] + a1[c] + a2[c] + a3[c];
    float* p = &OUT[(size_t)r * 40 + q * 8];
    *(float4*)(p)     = make_float4(o[0], o[1], o[2], o[3]);
    *(float4*)(p + 4) = make_float4(o[4], o[5], o[6], o[7]);
}

extern "C" void kernel_launch(void* const* d_in, const int* in_sizes, int n_in,
                              void* d_out, int out_size, void* d_ws, size_t ws_size,
                              hipStream_t stream) {
    const float* x  = (const float*)d_in[0];
    const int*   ei = (const int*)d_in[1];
    const float* W1 = (const float*)d_in[2];
    const float* b1 = (const float*)d_in[3];
    const float* W2 = (const float*)d_in[4];
    const float* b2 = (const float*)d_in[5];
    float* out = (float*)d_out;

    const int n = in_sizes[0] / 128;     // 50000
    const int m = in_sizes[1] / 2;       // 600000
    const int* src = ei;
    const int* dst = ei + m;
    const int nb = (n + 255) / 256;      // 196

    char* p = (char*)d_ws;
    auto take = [&](size_t bytes) { char* q = p; p += (bytes + 255) & ~(size_t)255; return q; };
    int*   cnt      = (int*)take(sizeof(int) * n);
    int*   rowstart = (int*)take(sizeof(int) * (n + 1));
    int*   cursor   = (int*)take(sizeof(int) * n);
    int*   bsum     = (int*)take(sizeof(int) * 256);
    int2*  epair    = (int2*)take(sizeof(int2) * m);
    float* dinv     = (float*)take(sizeof(float) * n);
    unsigned short* WT  = (unsigned short*)take(sizeof(short) * 128 * 128);
    unsigned short* WT2 = (unsigned short*)take(sizeof(short) * 48 * 128);
    unsigned short* H1b = (unsigned short*)take(sizeof(short) * (size_t)n * 128);
    unsigned short* AGGb = (unsigned short*)take(sizeof(short) * (size_t)n * 128);
    unsigned short* H3b = H1b;           // alias: H1b dead after k_agg1

    k_zero      <<<nb + 24, 256, 0, stream>>>(cnt, W1, W2, WT, WT2, n, nb);
    k_hist      <<<(m + 255) / 256, 256, 0, stream>>>(dst, cnt, m);
    k_scan_local<<<nb, 256, 0, stream>>>(cnt, rowstart, bsum, dinv, n);
    k_scan_add  <<<nb, 256, 0, stream>>>(rowstart, bsum, cursor, n, m, nb);
    k_scatter   <<<(m + 255) / 256, 256, 0, stream>>>(src, dst, dinv, cursor, epair, m);

    k_gemm1<<<(n + 63) / 64, 256, 0, stream>>>(x, WT, H1b, n);
    k_agg1 <<<(n + 15) / 16, 256, 0, stream>>>(rowstart, epair, H1b, b1, dinv, AGGb, n);
    k_gemm2<<<(n + 63) / 64, 256, 0, stream>>>(AGGb, WT2, H3b, n);
    k_agg2 <<<(n + 63) / 64, 320, 0, stream>>>(rowstart, epair, H3b, b2, dinv, out, n);
}